// Round 2
// baseline (577.062 us; speedup 1.0000x reference)
//
#include <hip/hip_runtime.h>

#define GN 8192
#define IN_DIM 512
#define ODIM 64
#define SLOPE 0.2f

typedef __attribute__((ext_vector_type(4))) float f32x4;
typedef __attribute__((ext_vector_type(4))) int   i32x4;
typedef __attribute__((ext_vector_type(8))) short bf16x8;

static __device__ __forceinline__ float bf2f(ushort u) {
    return __uint_as_float(((unsigned)u) << 16);
}
static __device__ __forceinline__ ushort f2bf(float f) {
    union { float f; unsigned u; } c; c.f = f;
    unsigned b = c.u;
    return (ushort)((b + 0x7fffu + ((b >> 16) & 1u)) >> 16);  // RNE
}

// Kernel 0: dtype detector. float32 N(0,1) words have exp field ~[97,134];
// packed-bf16 words reinterpreted as f32 have exp field >=~240 or <=~8.
extern "C" __global__ void gat_detect(const unsigned* __restrict__ xw,
                                      int* __restrict__ flag)
{
    if (threadIdx.x == 0) {
        int votes = 0;
        for (int t = 0; t < 64; ++t) {
            unsigned e = (xw[t] >> 23) & 0xffu;
            votes += (e > 60u && e < 180u) ? 1 : 0;
        }
        *flag = (votes >= 32) ? 1 : 0;   // 1 = float32 wire, 0 = bf16 wire
    }
}

// Kernel 1: Wh = x @ W^T (fp32 accum), s = Wh.a_src, d = Wh.a_dst,
// WhT (bf16, [dim][row]) for MFMA B-operand, global dmax via atomicMax.
extern "C" __global__ __launch_bounds__(64)
void gat_proj(const void* __restrict__ x_, const void* __restrict__ W_,
              const void* __restrict__ as_, const void* __restrict__ ad_,
              const int* __restrict__ flag,
              ushort* __restrict__ WhT, float* __restrict__ s_arr,
              float* __restrict__ d_arr, int* __restrict__ dmax_bits)
{
    __shared__ float xs[IN_DIM];
    const int i = blockIdx.x;
    const int lane = threadIdx.x;
    const int f32 = *flag;
    if (f32) {
        const f32x4* xr = (const f32x4*)((const float*)x_ + (size_t)i * IN_DIM);
        ((f32x4*)xs)[lane]      = xr[lane];
        ((f32x4*)xs)[64 + lane] = xr[64 + lane];
    } else {
        i32x4 raw = ((const i32x4*)((const ushort*)x_ + (size_t)i * IN_DIM))[lane];
        float* dst = xs + lane * 8;
        #pragma unroll
        for (int q = 0; q < 4; ++q) {
            dst[2 * q]     = __uint_as_float(((unsigned)raw[q]) << 16);
            dst[2 * q + 1] = __uint_as_float(((unsigned)raw[q]) & 0xffff0000u);
        }
    }
    __syncthreads();
    float acc = 0.f;
    if (f32) {
        const f32x4* Wr = (const f32x4*)((const float*)W_ + (size_t)lane * IN_DIM);
        #pragma unroll 8
        for (int k4 = 0; k4 < IN_DIM / 4; ++k4) {
            f32x4 wv = Wr[k4];
            f32x4 xv = ((const f32x4*)xs)[k4];
            acc = fmaf(xv[0], wv[0], acc);
            acc = fmaf(xv[1], wv[1], acc);
            acc = fmaf(xv[2], wv[2], acc);
            acc = fmaf(xv[3], wv[3], acc);
        }
    } else {
        const i32x4* Wr = (const i32x4*)((const ushort*)W_ + (size_t)lane * IN_DIM);
        #pragma unroll 4
        for (int k8 = 0; k8 < IN_DIM / 8; ++k8) {
            i32x4 wv = Wr[k8];
            const float* xp = xs + k8 * 8;
            #pragma unroll
            for (int q = 0; q < 4; ++q) {
                float w0 = __uint_as_float(((unsigned)wv[q]) << 16);
                float w1 = __uint_as_float(((unsigned)wv[q]) & 0xffff0000u);
                acc = fmaf(xp[2 * q], w0, acc);
                acc = fmaf(xp[2 * q + 1], w1, acc);
            }
        }
    }
    WhT[(size_t)lane * GN + i] = f2bf(acc);
    float av_s = f32 ? ((const float*)as_)[lane] : bf2f(((const ushort*)as_)[lane]);
    float av_d = f32 ? ((const float*)ad_)[lane] : bf2f(((const ushort*)ad_)[lane]);
    float ts = acc * av_s;
    float td = acc * av_d;
    #pragma unroll
    for (int off = 32; off > 0; off >>= 1) {
        ts += __shfl_xor(ts, off);
        td += __shfl_xor(td, off);
    }
    if (lane == 0) {
        s_arr[i] = ts;
        d_arr[i] = td;
        atomicMax(dmax_bits, __float_as_int(td));  // init 0 -> dmax >= max(0, max td): valid upper bound
    }
}

// Kernel 2: fused mask + leaky + exp + (alpha_unnorm @ Wh) via MFMA.
// Block = 256 thr (4 waves), 64 rows/block, 8-way j-split.
// A-frag layout (16x16x32 bf16): m = lane&15, k = (lane>>4)*8 + j  [m120]
// C/D layout: col = lane&15, row = (lane>>4)*4 + reg               [m89/m91]
extern "C" __global__ __launch_bounds__(256)
void gat_attn(const int* __restrict__ adj, const ushort* __restrict__ WhT,
              const float* __restrict__ s_arr, const float* __restrict__ d_arr,
              const int* __restrict__ dmax_bits,
              float* __restrict__ accum, float* __restrict__ lsum)
{
    const int JCH = GN / 8;                 // 1024 cols per j-split
    const int ib   = blockIdx.x & 127;
    const int js   = blockIdx.x >> 7;
    const int wave = threadIdx.x >> 6;
    const int lane = threadIdx.x & 63;
    const int quad = lane >> 4;
    const int lq   = lane & 15;
    const int i = ib * 64 + wave * 16 + lq; // this lane's A-row
    const float dmax = __int_as_float(*dmax_bits);
    const float si = s_arr[i];
    const float tb = si + dmax;
    const float mi = fmaxf(tb, SLOPE * tb); // upper bound on row logits (leaky monotone)
    const int jbase = js * JCH;
    f32x4 acc0 = {0,0,0,0}, acc1 = {0,0,0,0}, acc2 = {0,0,0,0}, acc3 = {0,0,0,0};
    float lacc = 0.f;
    const int* adjrow = adj + (size_t)i * GN;
    for (int jt = 0; jt < JCH; jt += 32) {
        const int j0 = jbase + jt + quad * 8;
        i32x4 av0 = *(const i32x4*)(adjrow + j0);
        i32x4 av1 = *(const i32x4*)(adjrow + j0 + 4);
        f32x4 dv0 = *(const f32x4*)(d_arr + j0);
        f32x4 dv1 = *(const f32x4*)(d_arr + j0 + 4);
        float w[8];
        #pragma unroll
        for (int q = 0; q < 4; ++q) {
            float e0 = si + dv0[q];
            e0 = fmaxf(e0, SLOPE * e0);          // leaky(x) = max(x, 0.2x)
            float v0 = __expf(e0 - mi);
            w[q] = (av0[q] > 0) ? v0 : 0.f;
            float e1 = si + dv1[q];
            e1 = fmaxf(e1, SLOPE * e1);
            float v1 = __expf(e1 - mi);
            w[4 + q] = (av1[q] > 0) ? v1 : 0.f;
        }
        bf16x8 af;
        #pragma unroll
        for (int q = 0; q < 8; ++q) {
            ushort wb = f2bf(w[q]);
            af[q] = (short)wb;
            lacc += bf2f(wb);   // denominator matches bf16 numerator scale exactly
        }
        // B-frag: b[j] = Wh[k = j0+j][n = nt*16+lq]  read from WhT[n][k] (contiguous 16B)
        bf16x8 b0 = *(const bf16x8*)(WhT + (size_t)(0 * 16 + lq) * GN + j0);
        bf16x8 b1 = *(const bf16x8*)(WhT + (size_t)(1 * 16 + lq) * GN + j0);
        bf16x8 b2 = *(const bf16x8*)(WhT + (size_t)(2 * 16 + lq) * GN + j0);
        bf16x8 b3 = *(const bf16x8*)(WhT + (size_t)(3 * 16 + lq) * GN + j0);
        acc0 = __builtin_amdgcn_mfma_f32_16x16x32_bf16(af, b0, acc0, 0, 0, 0);
        acc1 = __builtin_amdgcn_mfma_f32_16x16x32_bf16(af, b1, acc1, 0, 0, 0);
        acc2 = __builtin_amdgcn_mfma_f32_16x16x32_bf16(af, b2, acc2, 0, 0, 0);
        acc3 = __builtin_amdgcn_mfma_f32_16x16x32_bf16(af, b3, acc3, 0, 0, 0);
    }
    // row-sum of weights: reduce across quads sharing lq
    lacc += __shfl_xor(lacc, 16);
    lacc += __shfl_xor(lacc, 32);
    if (quad == 0) atomicAdd(&lsum[i], lacc);
    const int orow = ib * 64 + wave * 16 + quad * 4;
    #pragma unroll
    for (int r = 0; r < 4; ++r) {
        atomicAdd(&accum[(size_t)(orow + r) * ODIM +  0 + lq], acc0[r]);
        atomicAdd(&accum[(size_t)(orow + r) * ODIM + 16 + lq], acc1[r]);
        atomicAdd(&accum[(size_t)(orow + r) * ODIM + 32 + lq], acc2[r]);
        atomicAdd(&accum[(size_t)(orow + r) * ODIM + 48 + lq], acc3[r]);
    }
}

// Kernel 3: out = (accum / lsum), dtype per flag
extern "C" __global__ __launch_bounds__(256)
void gat_final(const float* __restrict__ accum, const float* __restrict__ lsum,
               const int* __restrict__ flag, void* __restrict__ out)
{
    const int idx = blockIdx.x * 256 + threadIdx.x;
    const float v = accum[idx] / lsum[idx >> 6];
    if (*flag) ((float*)out)[idx] = v;
    else       ((ushort*)out)[idx] = f2bf(v);
}

extern "C" void kernel_launch(void* const* d_in, const int* in_sizes, int n_in,
                              void* d_out, int out_size, void* d_ws, size_t ws_size,
                              hipStream_t stream)
{
    const void* x     = d_in[0];
    const int*  adj   = (const int*)d_in[1];
    const void* W     = d_in[2];
    const void* a_src = d_in[3];
    const void* a_dst = d_in[4];

    char* ws = (char*)d_ws;
    size_t off = 0;
    float* accum = (float*)(ws + off);  off += (size_t)GN * ODIM * 4;  // 2 MB
    float* lsum  = (float*)(ws + off);  off += (size_t)GN * 4;         // 32 KB
    int* dmax_bits = (int*)(ws + off);  off += 128;
    size_t zero_bytes = off;                                           // zero through dmax
    int* dflag = (int*)(ws + off);      off += 128;                    // written by detector
    float* s_arr = (float*)(ws + off);  off += (size_t)GN * 4;
    float* d_arr = (float*)(ws + off);  off += (size_t)GN * 4;
    ushort* WhT  = (ushort*)(ws + off); off += (size_t)ODIM * GN * 2;  // 1 MB

    hipMemsetAsync(ws, 0, zero_bytes, stream);
    gat_detect<<<1, 64, 0, stream>>>((const unsigned*)x, dflag);
    gat_proj<<<GN, 64, 0, stream>>>(x, W, a_src, a_dst, dflag, WhT, s_arr, d_arr, dmax_bits);
    gat_attn<<<1024, 256, 0, stream>>>(adj, WhT, s_arr, d_arr, dmax_bits, accum, lsum);
    gat_final<<<GN * ODIM / 256, 256, 0, stream>>>(accum, lsum, dflag, d_out);
}

// Round 3
// 488.320 us; speedup vs baseline: 1.1817x; 1.1817x over previous
//
#include <hip/hip_runtime.h>

#define GN 8192
#define IN_DIM 512
#define ODIM 64
#define SLOPE 0.2f

typedef __attribute__((ext_vector_type(4))) float  f32x4;
typedef __attribute__((ext_vector_type(4))) int    i32x4;
typedef __attribute__((ext_vector_type(8))) short  bf16x8;
typedef __attribute__((ext_vector_type(4))) unsigned short u16x4;

static __device__ __forceinline__ float bf2f(unsigned short u) {
    return __uint_as_float(((unsigned)u) << 16);
}
static __device__ __forceinline__ unsigned short f2bf(float f) {
    union { float f; unsigned u; } c; c.f = f;
    unsigned b = c.u;
    return (unsigned short)((b + 0x7fffu + ((b >> 16) & 1u)) >> 16);  // RNE
}

// Kernel 0: dtype detector. float32 N(0,1) words have exp field ~[97,134];
// packed-bf16 words reinterpreted as f32 have exp field >=~240 or <=~8.
// R2 evidence (gat_proj FETCH=8.7MB) says wire is bf16; detector kept for safety.
extern "C" __global__ void gat_detect(const unsigned* __restrict__ xw,
                                      int* __restrict__ flag)
{
    if (threadIdx.x == 0) {
        int votes = 0;
        for (int t = 0; t < 64; ++t) {
            unsigned e = (xw[t] >> 23) & 0xffu;
            votes += (e > 60u && e < 180u) ? 1 : 0;
        }
        *flag = (votes >= 32) ? 1 : 0;   // 1 = float32 wire, 0 = bf16 wire
    }
}

// load 8 contiguous elements as bf16x8, from either wire dtype
static __device__ __forceinline__ bf16x8 load8(const void* p, size_t off, int f32) {
    if (f32) {
        f32x4 lo = *(const f32x4*)((const float*)p + off);
        f32x4 hi = *(const f32x4*)((const float*)p + off + 4);
        bf16x8 r;
        #pragma unroll
        for (int q = 0; q < 4; ++q) {
            r[q]     = (short)f2bf(lo[q]);
            r[4 + q] = (short)f2bf(hi[q]);
        }
        return r;
    }
    return *(const bf16x8*)((const ushort*)p + off);
}

// Kernel 1 (MFMA GEMM): Wh = x @ W^T. Grid 128 x 256thr; 64 rows/block,
// 16 rows/wave; 4 n-tiles cover ODIM=64. Fused epilogue: s = Wh.a_src,
// d = Wh.a_dst (fp32, shuffle-reduced), WhT bf16 [dim][row], dmax atomicMax.
// A-frag: m=lane&15, k=quad*8+j. B-frag: n=lane&15, k=quad*8+j.
// C/D:    col=lane&15, row=quad*4+reg.   [verified working in R2 gat_attn]
extern "C" __global__ __launch_bounds__(256)
void gat_proj(const void* __restrict__ x_, const void* __restrict__ W_,
              const void* __restrict__ as_, const void* __restrict__ ad_,
              const int* __restrict__ flag,
              ushort* __restrict__ WhT, float* __restrict__ s_arr,
              float* __restrict__ d_arr, int* __restrict__ dmax_bits)
{
    const int wave = threadIdx.x >> 6;
    const int lane = threadIdx.x & 63;
    const int quad = lane >> 4;
    const int lq   = lane & 15;
    const int i0   = blockIdx.x * 64 + wave * 16;   // wave's 16-row tile base
    const int f32  = *flag;

    f32x4 acc[4] = {{0,0,0,0},{0,0,0,0},{0,0,0,0},{0,0,0,0}};
    const size_t arow = (size_t)(i0 + lq) * IN_DIM;
    #pragma unroll 2
    for (int k0 = 0; k0 < IN_DIM; k0 += 32) {
        const int kk = k0 + quad * 8;
        bf16x8 a  = load8(x_, arow + kk, f32);
        bf16x8 b0 = load8(W_, (size_t)( 0 + lq) * IN_DIM + kk, f32);
        bf16x8 b1 = load8(W_, (size_t)(16 + lq) * IN_DIM + kk, f32);
        bf16x8 b2 = load8(W_, (size_t)(32 + lq) * IN_DIM + kk, f32);
        bf16x8 b3 = load8(W_, (size_t)(48 + lq) * IN_DIM + kk, f32);
        acc[0] = __builtin_amdgcn_mfma_f32_16x16x32_bf16(a, b0, acc[0], 0, 0, 0);
        acc[1] = __builtin_amdgcn_mfma_f32_16x16x32_bf16(a, b1, acc[1], 0, 0, 0);
        acc[2] = __builtin_amdgcn_mfma_f32_16x16x32_bf16(a, b2, acc[2], 0, 0, 0);
        acc[3] = __builtin_amdgcn_mfma_f32_16x16x32_bf16(a, b3, acc[3], 0, 0, 0);
    }
    // lane holds Wh[i0 + quad*4 + r][t*16 + lq] in acc[t][r]
    float av_s[4], av_d[4];
    #pragma unroll
    for (int t = 0; t < 4; ++t) {
        const int n = t * 16 + lq;
        av_s[t] = f32 ? ((const float*)as_)[n] : bf2f(((const ushort*)as_)[n]);
        av_d[t] = f32 ? ((const float*)ad_)[n] : bf2f(((const ushort*)ad_)[n]);
    }
    // WhT write: pack 4 consecutive rows (r) per (t): 8B stores
    #pragma unroll
    for (int t = 0; t < 4; ++t) {
        u16x4 pk;
        #pragma unroll
        for (int r = 0; r < 4; ++r) pk[r] = f2bf(acc[t][r]);
        *(u16x4*)(WhT + (size_t)(t * 16 + lq) * GN + i0 + quad * 4) = pk;
    }
    // s/d: per-lane partials over the 4 n-tiles, reduce across lq (16 lanes)
    float ps[4], pd[4];
    #pragma unroll
    for (int r = 0; r < 4; ++r) {
        float s = 0.f, d = 0.f;
        #pragma unroll
        for (int t = 0; t < 4; ++t) {
            s = fmaf(acc[t][r], av_s[t], s);
            d = fmaf(acc[t][r], av_d[t], d);
        }
        #pragma unroll
        for (int off = 1; off < 16; off <<= 1) {
            s += __shfl_xor(s, off);
            d += __shfl_xor(d, off);
        }
        ps[r] = s; pd[r] = d;
    }
    if (lq == 0) {
        float dmx = -1e30f;
        #pragma unroll
        for (int r = 0; r < 4; ++r) {
            s_arr[i0 + quad * 4 + r] = ps[r];
            d_arr[i0 + quad * 4 + r] = pd[r];
            dmx = fmaxf(dmx, pd[r]);
        }
        if (dmx > 0.f) atomicMax(dmax_bits, __float_as_int(dmx));
    }
}

// Kernel 2: fused mask + leaky + exp + (alpha_unnorm @ Wh) via MFMA.
// Block = 256 thr (4 waves), 64 rows/block, 8-way j-split; 1-deep prefetch
// of adj+d for the next K-iter (clamped address, branchless).
extern "C" __global__ __launch_bounds__(256, 4)
void gat_attn(const int* __restrict__ adj, const ushort* __restrict__ WhT,
              const float* __restrict__ s_arr, const float* __restrict__ d_arr,
              const int* __restrict__ dmax_bits,
              float* __restrict__ accum, float* __restrict__ lsum)
{
    const int JCH = GN / 8;                 // 1024 cols per j-split
    const int ib   = blockIdx.x & 127;
    const int js   = blockIdx.x >> 7;
    const int wave = threadIdx.x >> 6;
    const int lane = threadIdx.x & 63;
    const int quad = lane >> 4;
    const int lq   = lane & 15;
    const int i = ib * 64 + wave * 16 + lq; // this lane's A-row
    const float dmax = __int_as_float(*dmax_bits);
    const float si = s_arr[i];
    const float tb = si + dmax;
    const float mi = fmaxf(tb, SLOPE * tb); // upper bound on row logits (leaky monotone)
    const int jbase = js * JCH;
    f32x4 acc0 = {0,0,0,0}, acc1 = {0,0,0,0}, acc2 = {0,0,0,0}, acc3 = {0,0,0,0};
    float lacc = 0.f;
    const int* adjrow = adj + (size_t)i * GN;
    const int iters = JCH / 32;             // 32

    int j0 = jbase + quad * 8;
    i32x4 av0 = *(const i32x4*)(adjrow + j0);
    i32x4 av1 = *(const i32x4*)(adjrow + j0 + 4);
    f32x4 dv0 = *(const f32x4*)(d_arr + j0);
    f32x4 dv1 = *(const f32x4*)(d_arr + j0 + 4);

    for (int it = 0; it < iters; ++it) {
        const int jc = j0;
        // prefetch next iteration (clamped to a valid address on last iter)
        const int jn = (it + 1 < iters) ? (j0 + 32) : (jbase + quad * 8);
        i32x4 nav0 = *(const i32x4*)(adjrow + jn);
        i32x4 nav1 = *(const i32x4*)(adjrow + jn + 4);
        f32x4 ndv0 = *(const f32x4*)(d_arr + jn);
        f32x4 ndv1 = *(const f32x4*)(d_arr + jn + 4);
        // B-frags for current iter, issued before the VALU block
        bf16x8 b0 = *(const bf16x8*)(WhT + (size_t)( 0 + lq) * GN + jc);
        bf16x8 b1 = *(const bf16x8*)(WhT + (size_t)(16 + lq) * GN + jc);
        bf16x8 b2 = *(const bf16x8*)(WhT + (size_t)(32 + lq) * GN + jc);
        bf16x8 b3 = *(const bf16x8*)(WhT + (size_t)(48 + lq) * GN + jc);

        float w[8];
        #pragma unroll
        for (int q = 0; q < 4; ++q) {
            float e0 = si + dv0[q];
            e0 = fmaxf(e0, SLOPE * e0);          // leaky(x) = max(x, 0.2x)
            float v0 = __expf(e0 - mi);
            w[q] = (av0[q] > 0) ? v0 : 0.f;
            float e1 = si + dv1[q];
            e1 = fmaxf(e1, SLOPE * e1);
            float v1 = __expf(e1 - mi);
            w[4 + q] = (av1[q] > 0) ? v1 : 0.f;
        }
        bf16x8 af;
        #pragma unroll
        for (int q = 0; q < 8; ++q) {
            unsigned short wb = f2bf(w[q]);
            af[q] = (short)wb;
            lacc += bf2f(wb);   // denominator matches bf16 numerator scale exactly
        }
        acc0 = __builtin_amdgcn_mfma_f32_16x16x32_bf16(af, b0, acc0, 0, 0, 0);
        acc1 = __builtin_amdgcn_mfma_f32_16x16x32_bf16(af, b1, acc1, 0, 0, 0);
        acc2 = __builtin_amdgcn_mfma_f32_16x16x32_bf16(af, b2, acc2, 0, 0, 0);
        acc3 = __builtin_amdgcn_mfma_f32_16x16x32_bf16(af, b3, acc3, 0, 0, 0);

        av0 = nav0; av1 = nav1; dv0 = ndv0; dv1 = ndv1;
        j0 += 32;
    }
    // row-sum of weights: reduce across quads sharing lq
    lacc += __shfl_xor(lacc, 16);
    lacc += __shfl_xor(lacc, 32);
    if (quad == 0) atomicAdd(&lsum[i], lacc);
    const int orow = ib * 64 + wave * 16 + quad * 4;
    #pragma unroll
    for (int r = 0; r < 4; ++r) {
        atomicAdd(&accum[(size_t)(orow + r) * ODIM +  0 + lq], acc0[r]);
        atomicAdd(&accum[(size_t)(orow + r) * ODIM + 16 + lq], acc1[r]);
        atomicAdd(&accum[(size_t)(orow + r) * ODIM + 32 + lq], acc2[r]);
        atomicAdd(&accum[(size_t)(orow + r) * ODIM + 48 + lq], acc3[r]);
    }
}

// Kernel 3: out = (accum / lsum), dtype per flag
extern "C" __global__ __launch_bounds__(256)
void gat_final(const float* __restrict__ accum, const float* __restrict__ lsum,
               const int* __restrict__ flag, void* __restrict__ out)
{
    const int idx = blockIdx.x * 256 + threadIdx.x;
    const float v = accum[idx] / lsum[idx >> 6];
    if (*flag) ((float*)out)[idx] = v;
    else       ((ushort*)out)[idx] = f2bf(v);
}

extern "C" void kernel_launch(void* const* d_in, const int* in_sizes, int n_in,
                              void* d_out, int out_size, void* d_ws, size_t ws_size,
                              hipStream_t stream)
{
    const void* x     = d_in[0];
    const int*  adj   = (const int*)d_in[1];
    const void* W     = d_in[2];
    const void* a_src = d_in[3];
    const void* a_dst = d_in[4];

    char* ws = (char*)d_ws;
    size_t off = 0;
    float* accum = (float*)(ws + off);  off += (size_t)GN * ODIM * 4;  // 2 MB
    float* lsum  = (float*)(ws + off);  off += (size_t)GN * 4;         // 32 KB
    int* dmax_bits = (int*)(ws + off);  off += 128;
    size_t zero_bytes = off;                                           // zero through dmax
    int* dflag = (int*)(ws + off);      off += 128;                    // written by detector
    float* s_arr = (float*)(ws + off);  off += (size_t)GN * 4;
    float* d_arr = (float*)(ws + off);  off += (size_t)GN * 4;
    ushort* WhT  = (ushort*)(ws + off); off += (size_t)ODIM * GN * 2;  // 1 MB

    hipMemsetAsync(ws, 0, zero_bytes, stream);
    gat_detect<<<1, 64, 0, stream>>>((const unsigned*)x, dflag);
    gat_proj<<<GN / 64, 256, 0, stream>>>(x, W, a_src, a_dst, dflag, WhT, s_arr, d_arr, dmax_bits);
    gat_attn<<<1024, 256, 0, stream>>>(adj, WhT, s_arr, d_arr, dmax_bits, accum, lsum);
    gat_final<<<GN * ODIM / 256, 256, 0, stream>>>(accum, lsum, dflag, d_out);
}

// Round 4
// 457.512 us; speedup vs baseline: 1.2613x; 1.0673x over previous
//
#include <hip/hip_runtime.h>

#define GN 8192
#define IN_DIM 512
#define ODIM 64
#define SLOPE 0.2f
#define PB 128                 // proj blocks (first, so they dispatch early)
#define CB 2048                // compress blocks
#define JSPLIT 16
#define JCH (GN / JSPLIT)      // 512 cols per j-split

typedef __attribute__((ext_vector_type(4))) float  f32x4;
typedef __attribute__((ext_vector_type(4))) int    i32x4;
typedef __attribute__((ext_vector_type(8))) short  bf16x8;
typedef __attribute__((ext_vector_type(4))) unsigned short u16x4;

static __device__ __forceinline__ float bf2f(unsigned short u) {
    return __uint_as_float(((unsigned)u) << 16);
}
static __device__ __forceinline__ unsigned short f2bf(float f) {
    union { float f; unsigned u; } c; c.f = f;
    unsigned b = c.u;
    return (unsigned short)((b + 0x7fffu + ((b >> 16) & 1u)) >> 16);  // RNE
}

// load 8 contiguous elements as bf16x8, from either wire dtype
static __device__ __forceinline__ bf16x8 load8(const void* p, size_t off, int f32) {
    if (f32) {
        f32x4 lo = *(const f32x4*)((const float*)p + off);
        f32x4 hi = *(const f32x4*)((const float*)p + off + 4);
        bf16x8 r;
        #pragma unroll
        for (int q = 0; q < 4; ++q) {
            r[q]     = (short)f2bf(lo[q]);
            r[4 + q] = (short)f2bf(hi[q]);
        }
        return r;
    }
    return *(const bf16x8*)((const ushort*)p + off);
}

// Fused kernel 1:
//  blocks [0,PB): MFMA GEMM Wh = x@W^T + epilogue (WhT bf16, s, d, dmax, dflag)
//  blocks [PB,PB+CB): adj -> bitmask compress (coalesced stream, ballot-pack)
extern "C" __global__ __launch_bounds__(256)
void gat_prep(const void* __restrict__ x_, const void* __restrict__ W_,
              const void* __restrict__ as_, const void* __restrict__ ad_,
              const int* __restrict__ adj, unsigned long long* __restrict__ bits64,
              ushort* __restrict__ WhT, float* __restrict__ s_arr,
              float* __restrict__ d_arr, int* __restrict__ dmax_bits,
              int* __restrict__ dflag)
{
    const int wave = threadIdx.x >> 6;
    const int lane = threadIdx.x & 63;

    if (blockIdx.x >= PB) {
        // ---- compress path: ballot-pack adj>0 into j-ordered bits ----
        const int wid = (blockIdx.x - PB) * 4 + wave;
        const size_t stride = (size_t)CB * 4 * 256;       // ints per sweep
        #pragma unroll 2
        for (int it = 0; it < 32; ++it) {                  // 67.1M / stride
            const size_t base = (size_t)wid * 256 + (size_t)it * stride;
            int a0 = adj[base +   0 + lane];               // coalesced 256B/instr
            int a1 = adj[base +  64 + lane];
            int a2 = adj[base + 128 + lane];
            int a3 = adj[base + 192 + lane];
            unsigned long long b0 = __ballot(a0 > 0);      // bit L = j (base+L)
            unsigned long long b1 = __ballot(a1 > 0);
            unsigned long long b2 = __ballot(a2 > 0);
            unsigned long long b3 = __ballot(a3 > 0);
            if (lane == 0) {
                ulonglong2* p = (ulonglong2*)(bits64 + base / 64);
                p[0] = make_ulonglong2(b0, b1);
                p[1] = make_ulonglong2(b2, b3);
            }
        }
        return;
    }

    // ---- proj path ----
    // per-wave dtype self-detect: f32 N(0,1) words have exp field ~[97,134]
    unsigned xw = ((const unsigned*)x_)[lane];
    unsigned ef = (xw >> 23) & 0xffu;
    unsigned long long vt = __ballot(ef > 60u && ef < 180u);
    const int f32 = (__popcll(vt) >= 32) ? 1 : 0;
    if (blockIdx.x == 0 && threadIdx.x == 0) *dflag = f32;

    const int quad = lane >> 4;
    const int lq   = lane & 15;
    const int i0   = blockIdx.x * 64 + wave * 16;   // wave's 16-row tile base

    f32x4 acc[4] = {{0,0,0,0},{0,0,0,0},{0,0,0,0},{0,0,0,0}};
    const size_t arow = (size_t)(i0 + lq) * IN_DIM;
    #pragma unroll 2
    for (int k0 = 0; k0 < IN_DIM; k0 += 32) {
        const int kk = k0 + quad * 8;
        bf16x8 a  = load8(x_, arow + kk, f32);
        bf16x8 b0 = load8(W_, (size_t)( 0 + lq) * IN_DIM + kk, f32);
        bf16x8 b1 = load8(W_, (size_t)(16 + lq) * IN_DIM + kk, f32);
        bf16x8 b2 = load8(W_, (size_t)(32 + lq) * IN_DIM + kk, f32);
        bf16x8 b3 = load8(W_, (size_t)(48 + lq) * IN_DIM + kk, f32);
        acc[0] = __builtin_amdgcn_mfma_f32_16x16x32_bf16(a, b0, acc[0], 0, 0, 0);
        acc[1] = __builtin_amdgcn_mfma_f32_16x16x32_bf16(a, b1, acc[1], 0, 0, 0);
        acc[2] = __builtin_amdgcn_mfma_f32_16x16x32_bf16(a, b2, acc[2], 0, 0, 0);
        acc[3] = __builtin_amdgcn_mfma_f32_16x16x32_bf16(a, b3, acc[3], 0, 0, 0);
    }
    // lane holds Wh[i0 + quad*4 + r][t*16 + lq] in acc[t][r]
    float av_s[4], av_d[4];
    #pragma unroll
    for (int t = 0; t < 4; ++t) {
        const int n = t * 16 + lq;
        av_s[t] = f32 ? ((const float*)as_)[n] : bf2f(((const ushort*)as_)[n]);
        av_d[t] = f32 ? ((const float*)ad_)[n] : bf2f(((const ushort*)ad_)[n]);
    }
    #pragma unroll
    for (int t = 0; t < 4; ++t) {
        u16x4 pk;
        #pragma unroll
        for (int r = 0; r < 4; ++r) pk[r] = f2bf(acc[t][r]);
        *(u16x4*)(WhT + (size_t)(t * 16 + lq) * GN + i0 + quad * 4) = pk;
    }
    float ps[4], pd[4];
    #pragma unroll
    for (int r = 0; r < 4; ++r) {
        float s = 0.f, d = 0.f;
        #pragma unroll
        for (int t = 0; t < 4; ++t) {
            s = fmaf(acc[t][r], av_s[t], s);
            d = fmaf(acc[t][r], av_d[t], d);
        }
        #pragma unroll
        for (int off = 1; off < 16; off <<= 1) {
            s += __shfl_xor(s, off);
            d += __shfl_xor(d, off);
        }
        ps[r] = s; pd[r] = d;
    }
    if (lq == 0) {
        float dmx = -1e30f;
        #pragma unroll
        for (int r = 0; r < 4; ++r) {
            s_arr[i0 + quad * 4 + r] = ps[r];
            d_arr[i0 + quad * 4 + r] = pd[r];
            dmx = fmaxf(dmx, pd[r]);
        }
        if (dmx > 0.f) atomicMax(dmax_bits, __float_as_int(dmx));
    }
}

// Kernel 2: fused mask(bits) + leaky + exp + (alpha_unnorm @ Wh) via MFMA.
// 2048 blocks = 128 ib x 16 js. Per lane: 16B bit-load serves 4 K-iters.
// A-frag: m=lane&15, k=quad*8+j. C/D: col=lane&15, row=quad*4+reg.
extern "C" __global__ __launch_bounds__(256, 4)
void gat_attn(const unsigned* __restrict__ bits32, const ushort* __restrict__ WhT,
              const float* __restrict__ s_arr, const float* __restrict__ d_arr,
              const int* __restrict__ dmax_bits,
              float* __restrict__ accum, float* __restrict__ lsum)
{
    const int ib   = blockIdx.x & 127;
    const int js   = blockIdx.x >> 7;        // 0..15
    const int wave = threadIdx.x >> 6;
    const int lane = threadIdx.x & 63;
    const int quad = lane >> 4;
    const int lq   = lane & 15;
    const int i = ib * 64 + wave * 16 + lq;  // this lane's A-row
    const float dmax = __int_as_float(*dmax_bits);
    const float si = s_arr[i];
    const float tb = si + dmax;
    const float mi = fmaxf(tb, SLOPE * tb);  // upper bound on row logits
    const int jbase = js * JCH;
    f32x4 acc0 = {0,0,0,0}, acc1 = {0,0,0,0}, acc2 = {0,0,0,0}, acc3 = {0,0,0,0};
    float lacc = 0.f;
    // row i's bit words for this j-chunk: 16 u32 = 4 x 16B
    const unsigned* bitrow = bits32 + (size_t)i * (GN / 32) + js * (JCH / 32);

    #pragma unroll 1
    for (int it4 = 0; it4 < JCH / 128; ++it4) {          // 4 outer iters
        i32x4 bw = *(const i32x4*)(bitrow + it4 * 4);    // bits for 128 j
        #pragma unroll
        for (int sub = 0; sub < 4; ++sub) {
            const int it = it4 * 4 + sub;
            const int j0 = jbase + it * 32 + quad * 8;   // this lane's 8 j's
            const unsigned m8 = (((unsigned)bw[sub]) >> (quad * 8)) & 0xffu;
            f32x4 dv0 = *(const f32x4*)(d_arr + j0);
            f32x4 dv1 = *(const f32x4*)(d_arr + j0 + 4);
            bf16x8 b0 = *(const bf16x8*)(WhT + (size_t)( 0 + lq) * GN + j0);
            bf16x8 b1 = *(const bf16x8*)(WhT + (size_t)(16 + lq) * GN + j0);
            bf16x8 b2 = *(const bf16x8*)(WhT + (size_t)(32 + lq) * GN + j0);
            bf16x8 b3 = *(const bf16x8*)(WhT + (size_t)(48 + lq) * GN + j0);
            float w[8];
            #pragma unroll
            for (int q = 0; q < 4; ++q) {
                float e0 = si + dv0[q];
                e0 = fmaxf(e0, SLOPE * e0);              // leaky
                float v0 = __expf(e0 - mi);
                w[q] = ((m8 >> q) & 1u) ? v0 : 0.f;
                float e1 = si + dv1[q];
                e1 = fmaxf(e1, SLOPE * e1);
                float v1 = __expf(e1 - mi);
                w[4 + q] = ((m8 >> (4 + q)) & 1u) ? v1 : 0.f;
            }
            bf16x8 af;
            #pragma unroll
            for (int q = 0; q < 8; ++q) {
                unsigned short wb = f2bf(w[q]);
                af[q] = (short)wb;
                lacc += bf2f(wb);   // denominator matches bf16 numerator exactly
            }
            acc0 = __builtin_amdgcn_mfma_f32_16x16x32_bf16(af, b0, acc0, 0, 0, 0);
            acc1 = __builtin_amdgcn_mfma_f32_16x16x32_bf16(af, b1, acc1, 0, 0, 0);
            acc2 = __builtin_amdgcn_mfma_f32_16x16x32_bf16(af, b2, acc2, 0, 0, 0);
            acc3 = __builtin_amdgcn_mfma_f32_16x16x32_bf16(af, b3, acc3, 0, 0, 0);
        }
    }
    lacc += __shfl_xor(lacc, 16);
    lacc += __shfl_xor(lacc, 32);
    if (quad == 0) atomicAdd(&lsum[i], lacc);
    const int orow = ib * 64 + wave * 16 + quad * 4;
    #pragma unroll
    for (int r = 0; r < 4; ++r) {
        atomicAdd(&accum[(size_t)(orow + r) * ODIM +  0 + lq], acc0[r]);
        atomicAdd(&accum[(size_t)(orow + r) * ODIM + 16 + lq], acc1[r]);
        atomicAdd(&accum[(size_t)(orow + r) * ODIM + 32 + lq], acc2[r]);
        atomicAdd(&accum[(size_t)(orow + r) * ODIM + 48 + lq], acc3[r]);
    }
}

// Kernel 3: out = (accum / lsum), dtype per flag
extern "C" __global__ __launch_bounds__(256)
void gat_final(const float* __restrict__ accum, const float* __restrict__ lsum,
               const int* __restrict__ flag, void* __restrict__ out)
{
    const int idx = blockIdx.x * 256 + threadIdx.x;
    const float v = accum[idx] / lsum[idx >> 6];
    if (*flag) ((float*)out)[idx] = v;
    else       ((ushort*)out)[idx] = f2bf(v);
}

extern "C" void kernel_launch(void* const* d_in, const int* in_sizes, int n_in,
                              void* d_out, int out_size, void* d_ws, size_t ws_size,
                              hipStream_t stream)
{
    const void* x     = d_in[0];
    const int*  adj   = (const int*)d_in[1];
    const void* W     = d_in[2];
    const void* a_src = d_in[3];
    const void* a_dst = d_in[4];

    char* ws = (char*)d_ws;
    size_t off = 0;
    float* accum = (float*)(ws + off);  off += (size_t)GN * ODIM * 4;      // 2 MB
    float* lsum  = (float*)(ws + off);  off += (size_t)GN * 4;             // 32 KB
    int* dmax_bits = (int*)(ws + off);  off += 128;
    size_t zero_bytes = off;                                               // zero through dmax
    int* dflag = (int*)(ws + off);      off += 128;                        // written by gat_prep
    float* s_arr = (float*)(ws + off);  off += (size_t)GN * 4;
    float* d_arr = (float*)(ws + off);  off += (size_t)GN * 4;
    ushort* WhT  = (ushort*)(ws + off); off += (size_t)ODIM * GN * 2;      // 1 MB
    unsigned long long* bits = (unsigned long long*)(ws + off);
    off += (size_t)GN * GN / 8;                                            // 8 MB

    hipMemsetAsync(ws, 0, zero_bytes, stream);
    gat_prep<<<PB + CB, 256, 0, stream>>>(x, W, a_src, a_dst, adj, bits,
                                          WhT, s_arr, d_arr, dmax_bits, dflag);
    gat_attn<<<128 * JSPLIT, 256, 0, stream>>>((const unsigned*)bits, WhT,
                                               s_arr, d_arr, dmax_bits, accum, lsum);
    gat_final<<<GN * ODIM / 256, 256, 0, stream>>>(accum, lsum, dflag, d_out);
}